// Round 10
// baseline (312.512 us; speedup 1.0000x reference)
//
#include <hip/hip_runtime.h>
#include <math.h>

#define D_MODEL 768
#define NUM_HEADS 12
#define HEAD_DIM 64
#define SEQ 2048
#define BATCH 4
#define MROWS (BATCH * SEQ)   // 8192
#define HALF_D (D_MODEL / 2)  // 384

typedef __bf16 bf16x8 __attribute__((ext_vector_type(8)));
typedef __bf16 bf16x4 __attribute__((ext_vector_type(4)));
typedef float  f32x4  __attribute__((ext_vector_type(4)));

// async global->LDS, 16B per lane; LDS dest = wave-uniform base + lane*16
__device__ __forceinline__ void gload_lds16(const void* gp, void* lp) {
    __builtin_amdgcn_global_load_lds(
        (const __attribute__((address_space(1))) unsigned int*)gp,
        (__attribute__((address_space(3))) unsigned int*)lp, 16, 0, 0);
}

// ---------------------------------------------------------------------------
// RoPE table: tab[s][j] = (cos, sin). Transcendental calls only here.
// ---------------------------------------------------------------------------
__global__ __launch_bounds__(256)
void rope_table(float2* __restrict__ tab)
{
    int idx = blockIdx.x * 256 + threadIdx.x;      // s*384 + j
    int s = idx / HALF_D;
    int j = idx - s * HALF_D;
    float freq = __expf(-(float)j * (9.210340371976184f / 384.0f));
    float ang  = (float)s * freq;
    float sn, cs;
    sincosf(ang, &sn, &cs);
    tab[idx] = make_float2(cs, sn);
}

// ---------------------------------------------------------------------------
// Cast X fp32 -> bf16 row-major
// ---------------------------------------------------------------------------
__global__ __launch_bounds__(256)
void cast_x(const float* __restrict__ X, __bf16* __restrict__ Xb)
{
    size_t i = ((size_t)blockIdx.x * 256 + threadIdx.x) * 8;
    float4 u = *(const float4*)(X + i);
    float4 v = *(const float4*)(X + i + 4);
    bf16x8 o;
    o[0]=(__bf16)u.x; o[1]=(__bf16)u.y; o[2]=(__bf16)u.z; o[3]=(__bf16)u.w;
    o[4]=(__bf16)v.x; o[5]=(__bf16)v.y; o[6]=(__bf16)v.z; o[7]=(__bf16)v.w;
    *(bf16x8*)(Xb + i) = o;
}

// ---------------------------------------------------------------------------
// Cast + transpose weights: Wt[n][k] = (bf16)W[k][n].
// ---------------------------------------------------------------------------
__global__ __launch_bounds__(256)
void wcast(const float* __restrict__ W0, const float* __restrict__ W1,
           const float* __restrict__ W2, const float* __restrict__ W3,
           __bf16* __restrict__ T0, __bf16* __restrict__ T1,
           __bf16* __restrict__ T2, __bf16* __restrict__ T3)
{
    __shared__ float t[64][65];
    const int z = blockIdx.z;
    const float* W = z == 0 ? W0 : z == 1 ? W1 : z == 2 ? W2 : W3;
    __bf16*      T = z == 0 ? T0 : z == 1 ? T1 : z == 2 ? T2 : T3;

    const int tid = threadIdx.x;
    const int r0 = blockIdx.y * 64, c0 = blockIdx.x * 64;
    const int lx = tid & 63, g = tid >> 6;

    #pragma unroll
    for (int rr = 0; rr < 16; ++rr) {
        int r = g * 16 + rr;
        t[r][lx] = W[(size_t)(r0 + r) * D_MODEL + c0 + lx];
    }
    __syncthreads();

    const int n  = tid >> 2;
    const int kb = (tid & 3) * 16;
    bf16x8 o1, o2;
    #pragma unroll
    for (int m = 0; m < 8; ++m) o1[m] = (__bf16)t[kb + m][n];
    #pragma unroll
    for (int m = 0; m < 8; ++m) o2[m] = (__bf16)t[kb + 8 + m][n];
    __bf16* dst = T + (size_t)(c0 + n) * D_MODEL + r0 + kb;
    *(bf16x8*)dst       = o1;
    *(bf16x8*)(dst + 8) = o2;
}

// ---------------------------------------------------------------------------
// Fused QKV projection v4: BARRIER-FREE K-loop.
// Block = 32 rows x 256 cols, 4 waves (each 32x64). The block's A strip
// (32x768 = 49 KB) is staged to LDS ONCE (single barrier), laid out in
// fragment order. The 24-step K-loop has NO barriers: each wave streams its
// own B fragments global->VGPR (weights total 3.5 MB -> resident in every
// XCD L2, ~200cyc) with a 3-buffer 2-deep pipeline + 2 ds_read_b128 A-frags
// + 8 MFMA per step. R6/R7/R9 all pinned at ~92us by the per-step barrier's
// vmcnt(0) drain; this removes the drain entirely.
// grid: 2304 = c*256 + rowtile;  c = which*3 + colchunk (256 cols each).
// ---------------------------------------------------------------------------
__global__ __launch_bounds__(256)
void qkv_gemm(const __bf16* __restrict__ Xb,
              const __bf16* __restrict__ Wqt, const __bf16* __restrict__ Wkt,
              const __bf16* __restrict__ Wvt,
              const float* __restrict__ bq, const float* __restrict__ bk,
              const float* __restrict__ bv,
              const float2* __restrict__ tab,
              __bf16* __restrict__ Qb, __bf16* __restrict__ Kb,
              __bf16* __restrict__ Vtb)
{
    __shared__ bf16x8 Af[48][64];       // 49 KB: chunk id = s*2+i, frag order

    const int tid  = threadIdx.x;
    const int wv   = tid >> 6;          // 0..3 -> col strip 64*wv
    const int ln   = tid & 63;
    const int t15  = ln & 15;
    const int quad = ln >> 4;

    const int lin  = blockIdx.x;        // 2304: c*256 + r
    const int c    = lin >> 8;          // 0..8
    const int r    = lin & 255;         // row tile
    const int which = c / 3;            // 0=Q 1=K 2=V
    const int col0  = (c % 3) * 256;
    const int row0  = r * 32;

    const __bf16* Wt  = which == 0 ? Wqt : which == 1 ? Wkt : Wvt;
    const float* bias = which == 0 ? bq  : which == 1 ? bk  : bv;

    // ---- stage A strip (32 rows x 768) to LDS, fragment order, ONE barrier ----
    #pragma unroll
    for (int cc = 0; cc < 12; ++cc) {
        const int id = wv * 12 + cc;         // 0..47 = s*2 + i
        const int s  = id >> 1;
        const int i  = id & 1;
        const __bf16* src = Xb + (size_t)(row0 + 16 * i + t15) * D_MODEL + 32 * s + 8 * quad;
        gload_lds16(src, &Af[id][0]);
    }
    __syncthreads();

    // ---- B stream pointers (wave-private 64 cols; frag j: cols 16j..16j+15) ----
    const __bf16* Bbase = Wt + (size_t)(col0 + 64 * wv + t15) * D_MODEL + 8 * quad;

    f32x4 acc[2][4];
    #pragma unroll
    for (int i = 0; i < 2; ++i)
        #pragma unroll
        for (int j = 0; j < 4; ++j) acc[i][j] = (f32x4){0.f,0.f,0.f,0.f};

    bf16x8 bfr[3][4];                    // 3-buffer, 2-deep pipeline
    #pragma unroll
    for (int j = 0; j < 4; ++j) {
        bfr[0][j] = *(const bf16x8*)(Bbase + (size_t)(16 * j) * D_MODEL);
        bfr[1][j] = *(const bf16x8*)(Bbase + (size_t)(16 * j) * D_MODEL + 32);
    }

    #pragma unroll
    for (int s = 0; s < 24; ++s) {       // NO barriers in this loop
        const int cur = s % 3;
        if (s + 2 < 24) {
            const int kn = (s + 2) * 32;
            const int nb = (s + 2) % 3;
            #pragma unroll
            for (int j = 0; j < 4; ++j)
                bfr[nb][j] = *(const bf16x8*)(Bbase + (size_t)(16 * j) * D_MODEL + kn);
        }
        bf16x8 af0 = Af[2 * s][ln];
        bf16x8 af1 = Af[2 * s + 1][ln];
        #pragma unroll
        for (int j = 0; j < 4; ++j) {
            acc[0][j] = __builtin_amdgcn_mfma_f32_16x16x32_bf16(af0, bfr[cur][j], acc[0][j], 0, 0, 0);
            acc[1][j] = __builtin_amdgcn_mfma_f32_16x16x32_bf16(af1, bfr[cur][j], acc[1][j], 0, 0, 0);
        }
    }

    // ---- epilogue ----
    #pragma unroll
    for (int i = 0; i < 2; ++i) {
        const int rowb = row0 + 16 * i + 4 * quad;
        #pragma unroll
        for (int j = 0; j < 4; ++j) {
            const int col = col0 + 64 * wv + 16 * j + t15;
            const float bval = bias[col];
            if (which < 2) {
                const int jh  = col >> 1;
                const float sgn = (col & 1) ? 1.0f : -1.0f;
                const float oscale = (which == 0) ? 0.125f : 1.0f;  // fold 1/sqrt(64) into Q
                __bf16* dst = (which ? Kb : Qb);
                #pragma unroll
                for (int rr = 0; rr < 4; ++rr) {
                    const int rw = rowb + rr;
                    const int s  = rw & (SEQ - 1);
                    float val  = acc[i][j][rr] + bval;
                    float part = __shfl_xor(val, 1, 64);
                    float2 cs  = tab[(size_t)s * HALF_D + jh];
                    dst[(size_t)rw * D_MODEL + col] = (__bf16)((val * cs.x + part * sgn * cs.y) * oscale);
                }
            } else {
                const int h = col >> 6, d = col & 63;
                const int bidx = rowb >> 11, s = rowb & (SEQ - 1);
                bf16x4 pk;
                #pragma unroll
                for (int rr = 0; rr < 4; ++rr) pk[rr] = (__bf16)(acc[i][j][rr] + bval);
                *(bf16x4*)(Vtb + ((size_t)(bidx * NUM_HEADS + h) * 64 + d) * SEQ + s) = pk;
            }
        }
    }
}

// ---------------------------------------------------------------------------
// Output projection v3 (unchanged from R9): BK=64 cooperative, XCD-swizzled.
// ---------------------------------------------------------------------------
__global__ __launch_bounds__(256)
void out_gemm(const __bf16* __restrict__ Ab, const __bf16* __restrict__ Wt,
              const float* __restrict__ bias, float* __restrict__ Cout)
{
    __shared__ bf16x8 Asf[2][8][64];
    __shared__ bf16x8 Bsf[2][8][64];

    const int tid  = threadIdx.x;
    const int wv   = tid >> 6;
    const int ln   = tid & 63;
    const int t15  = ln & 15;
    const int quad = ln >> 4;
    const int wr = wv >> 1, wc = wv & 1;

    const int lin = blockIdx.x;          // 384 blocks: c*64 + r
    const int col0 = (lin >> 6) * 128;
    const int row0 = (lin & 63) * 128;

    f32x4 acc[4][4];
    #pragma unroll
    for (int i = 0; i < 4; ++i)
        #pragma unroll
        for (int j = 0; j < 4; ++j) acc[i][j] = (f32x4){0.f,0.f,0.f,0.f};

    const __bf16* a0 = Ab + (size_t)(row0 + 16 * wv       + t15) * D_MODEL + 8 * quad;
    const __bf16* a1 = Ab + (size_t)(row0 + 16 * (wv + 4) + t15) * D_MODEL + 8 * quad;
    const __bf16* b0 = Wt + (size_t)(col0 + 16 * wv       + t15) * D_MODEL + 8 * quad;
    const __bf16* b1 = Wt + (size_t)(col0 + 16 * (wv + 4) + t15) * D_MODEL + 8 * quad;

    for (int k0 = 0; k0 < D_MODEL; k0 += 64) {
        __syncthreads();
        #pragma unroll
        for (int ks = 0; ks < 2; ++ks) {
            const int kk = k0 + 32 * ks;
            gload_lds16(a0 + kk, &Asf[ks][wv][0]);
            gload_lds16(a1 + kk, &Asf[ks][wv + 4][0]);
            gload_lds16(b0 + kk, &Bsf[ks][wv][0]);
            gload_lds16(b1 + kk, &Bsf[ks][wv + 4][0]);
        }
        __syncthreads();

        #pragma unroll
        for (int ks = 0; ks < 2; ++ks) {
            bf16x8 af[4], bfr[4];
            #pragma unroll
            for (int i = 0; i < 4; ++i) af[i]  = Asf[ks][4 * wr + i][ln];
            #pragma unroll
            for (int j = 0; j < 4; ++j) bfr[j] = Bsf[ks][4 * wc + j][ln];
            #pragma unroll
            for (int i = 0; i < 4; ++i)
                #pragma unroll
                for (int j = 0; j < 4; ++j)
                    acc[i][j] = __builtin_amdgcn_mfma_f32_16x16x32_bf16(af[i], bfr[j], acc[i][j], 0, 0, 0);
        }
    }

    #pragma unroll
    for (int i = 0; i < 4; ++i) {
        const int rowb = row0 + 64 * wr + 16 * i + 4 * quad;
        #pragma unroll
        for (int j = 0; j < 4; ++j) {
            const int col = col0 + 64 * wc + 16 * j + t15;
            const float bval = bias[col];
            #pragma unroll
            for (int rr = 0; rr < 4; ++rr)
                Cout[(size_t)(rowb + rr) * D_MODEL + col] = acc[i][j][rr] + bval;
        }
    }
}

// ---------------------------------------------------------------------------
// Flash attention v3 (unchanged from R6): 128-query blocks, 8 waves, no-max
// softmax, lane-local l, double-buffered K/V, P as bf16 via per-wave LDS.
// ---------------------------------------------------------------------------
__device__ __forceinline__ void attn_tile(
    const bf16x8 (*Kbuf)[64], const bf16x8 (*Vbuf)[64],
    __bf16 (*Psw)[72],
    bf16x8 aq0, bf16x8 aq1,
    f32x4* o, float* lacc,
    int ln, int t15, int quad, int j0, int qabs, bool domask)
{
    f32x4 s[4];
    #pragma unroll
    for (int c = 0; c < 4; ++c) {
        s[c] = (f32x4){0.f, 0.f, 0.f, 0.f};
        s[c] = __builtin_amdgcn_mfma_f32_16x16x32_bf16(aq0, Kbuf[c][ln],     s[c], 0, 0, 0);
        s[c] = __builtin_amdgcn_mfma_f32_16x16x32_bf16(aq1, Kbuf[4 + c][ln], s[c], 0, 0, 0);
    }

    float p[4][4];
    #pragma unroll
    for (int c = 0; c < 4; ++c)
        #pragma unroll
        for (int r = 0; r < 4; ++r) {
            float e = __expf(s[c][r]);
            if (domask && (j0 + 16 * c + t15 > qabs + r)) e = 0.f;
            p[c][r] = e;
            lacc[r] += e;
        }

    #pragma unroll
    for (int c = 0; c < 4; ++c)
        #pragma unroll
        for (int r = 0; r < 4; ++r)
            Psw[4 * quad + r][16 * c + t15] = (__bf16)p[c][r];
    __asm__ volatile("s_waitcnt lgkmcnt(0)" ::: "memory");

    bf16x8 ap0 = *(const bf16x8*)&Psw[t15][8 * quad];
    bf16x8 ap1 = *(const bf16x8*)&Psw[t15][32 + 8 * quad];

    #pragma unroll
    for (int c = 0; c < 4; ++c) {
        o[c] = __builtin_amdgcn_mfma_f32_16x16x32_bf16(ap0, Vbuf[c][ln],     o[c], 0, 0, 0);
        o[c] = __builtin_amdgcn_mfma_f32_16x16x32_bf16(ap1, Vbuf[4 + c][ln], o[c], 0, 0, 0);
    }
}

__global__ __launch_bounds__(512)
void attn_flash(const __bf16* __restrict__ Q, const __bf16* __restrict__ K,
                const __bf16* __restrict__ Vt, __bf16* __restrict__ O)
{
    __shared__ bf16x8 Kf[2][8][64];     // 16 KB (double-buffered)
    __shared__ bf16x8 Vf[2][8][64];     // 16 KB
    __shared__ __bf16 Psb[8][16][72];   // 18.4 KB

    const int tid  = threadIdx.x;
    const int wv   = tid >> 6;
    const int ln   = tid & 63;
    const int t15  = ln & 15;
    const int quad = ln >> 4;

    const int n  = blockIdx.x;
    const int sb = n >> 8;
    const int tb = n & 255;
    const int a  = tb & 15;
    const int qt = (sb == 0) ? a : (sb == 1) ? (15 - a) : ((a + 8) & 15);
    const int bh = (tb >> 4) + 16 * sb;
    const int b  = bh / NUM_HEADS;
    const int h  = bh % NUM_HEADS;
    const int q0 = qt * 128;
    const int nt = (q0 >> 6) + 2;

    bf16x8 aq0, aq1;
    {
        const __bf16* qs = Q + (size_t)(b * SEQ + q0 + 16 * wv + t15) * D_MODEL + h * 64 + 8 * quad;
        aq0 = *(const bf16x8*)qs;
        aq1 = *(const bf16x8*)(qs + 32);
    }

    const __bf16* kp = K  + ((size_t)b * SEQ + 16 * (wv & 3) + t15) * D_MODEL
                          + h * 64 + 32 * (wv >> 2) + 8 * quad;
    const __bf16* vp = Vt + ((size_t)bh * 64 + 16 * (wv & 3) + t15) * SEQ
                          + 32 * (wv >> 2) + 8 * quad;

    f32x4 o[4];
    #pragma unroll
    for (int c = 0; c < 4; ++c) o[c] = (f32x4){0.f,0.f,0.f,0.f};
    float lacc[4] = {0.f, 0.f, 0.f, 0.f};
    const int qabs = q0 + 16 * wv + 4 * quad;

    gload_lds16(kp, &Kf[0][wv][0]);
    gload_lds16(vp, &Vf[0][wv][0]);

    int cur = 0;
    for (int it = 0; it < nt; ++it) {
        __syncthreads();
        if (it + 1 < nt) {
            const int jn = (it + 1) * 64;
            gload_lds16(kp + (size_t)jn * D_MODEL, &Kf[cur ^ 1][wv][0]);
            gload_lds16(vp + jn,                   &Vf[cur ^ 1][wv][0]);
        }
        const int j0 = it * 64;
        const bool domask = (j0 + 63) > (q0 + 16 * wv);
        attn_tile(Kf[cur], Vf[cur], Psb[wv], aq0, aq1, o, lacc,
                  ln, t15, quad, j0, qabs, domask);
        cur ^= 1;
    }

    #pragma unroll
    for (int off = 1; off < 16; off <<= 1)
        #pragma unroll
        for (int r = 0; r < 4; ++r)
            lacc[r] += __shfl_xor(lacc[r], off, 64);

    float inv[4];
    #pragma unroll
    for (int r = 0; r < 4; ++r) inv[r] = 1.0f / lacc[r];
    #pragma unroll
    for (int c = 0; c < 4; ++c)
        #pragma unroll
        for (int r = 0; r < 4; ++r) {
            int row = qabs + r;
            O[(size_t)(b * SEQ + row) * D_MODEL + h * 64 + 16 * c + t15] = (__bf16)(o[c][r] * inv[r]);
        }
}

// ---------------------------------------------------------------------------
extern "C" void kernel_launch(void* const* d_in, const int* in_sizes, int n_in,
                              void* d_out, int out_size, void* d_ws, size_t ws_size,
                              hipStream_t stream) {
    const float* X  = (const float*)d_in[0];
    const float* Wq = (const float*)d_in[1];
    const float* bq = (const float*)d_in[2];
    const float* Wk = (const float*)d_in[3];
    const float* bk = (const float*)d_in[4];
    const float* Wv = (const float*)d_in[5];
    const float* bv = (const float*)d_in[6];
    const float* Wo = (const float*)d_in[7];
    const float* bo = (const float*)d_in[8];
    float* out = (float*)d_out;

    const size_t BSD = (size_t)MROWS * D_MODEL;   // 6,291,456
    const size_t WSZ = (size_t)D_MODEL * D_MODEL; //   589,824

    __bf16* Xb  = (__bf16*)d_ws;
    __bf16* Qb  = Xb  + BSD;
    __bf16* Kb  = Qb  + BSD;
    __bf16* Vtb = Kb  + BSD;
    __bf16* Ob  = Vtb + BSD;
    __bf16* Wqt = Ob  + BSD;
    __bf16* Wkt = Wqt + WSZ;
    __bf16* Wvt = Wkt + WSZ;
    __bf16* Wot = Wvt + WSZ;
    float2* Tab = (float2*)(Wot + WSZ);

    rope_table<<<(SEQ * HALF_D) / 256, 256, 0, stream>>>(Tab);
    cast_x<<<BSD / (256 * 8), 256, 0, stream>>>(X, Xb);
    wcast<<<dim3(12, 12, 4), 256, 0, stream>>>(Wq, Wk, Wv, Wo, Wqt, Wkt, Wvt, Wot);

    qkv_gemm<<<2304, 256, 0, stream>>>(Xb, Wqt, Wkt, Wvt, bq, bk, bv, Tab, Qb, Kb, Vtb);

    attn_flash<<<768, 512, 0, stream>>>(Qb, Kb, Vtb, Ob);

    out_gemm<<<384, 256, 0, stream>>>(Ob, Wot, bo, out);
}

// Round 11
// 264.034 us; speedup vs baseline: 1.1836x; 1.1836x over previous
//
#include <hip/hip_runtime.h>
#include <math.h>

#define D_MODEL 768
#define NUM_HEADS 12
#define HEAD_DIM 64
#define SEQ 2048
#define BATCH 4
#define MROWS (BATCH * SEQ)   // 8192
#define HALF_D (D_MODEL / 2)  // 384

typedef __bf16 bf16x8 __attribute__((ext_vector_type(8)));
typedef __bf16 bf16x4 __attribute__((ext_vector_type(4)));
typedef float  f32x4  __attribute__((ext_vector_type(4)));

// async global->LDS, 16B per lane; LDS dest = wave-uniform base + lane*16
__device__ __forceinline__ void gload_lds16(const void* gp, void* lp) {
    __builtin_amdgcn_global_load_lds(
        (const __attribute__((address_space(1))) unsigned int*)gp,
        (__attribute__((address_space(3))) unsigned int*)lp, 16, 0, 0);
}

// ---------------------------------------------------------------------------
// prep: one launch for RoPE table (blocks [0,3072)), X cast ([3072,6144)),
// and weight cast+transpose ([6144,6720)). All independent; merging saves
// 2 launch/gap overheads and lets the parts co-schedule.
// ---------------------------------------------------------------------------
__global__ __launch_bounds__(256)
void prep(const float* __restrict__ X, __bf16* __restrict__ Xb,
          const float* __restrict__ W0, const float* __restrict__ W1,
          const float* __restrict__ W2, const float* __restrict__ W3,
          __bf16* __restrict__ T0, __bf16* __restrict__ T1,
          __bf16* __restrict__ T2, __bf16* __restrict__ T3,
          float2* __restrict__ tab)
{
    __shared__ float t[64][65];
    const int n   = blockIdx.x;
    const int tid = threadIdx.x;

    if (n < 3072) {
        // ---- RoPE table: tab[s][j] = (cos, sin) ----
        int idx = n * 256 + tid;               // s*384 + j
        int s = idx / HALF_D;
        int j = idx - s * HALF_D;
        float freq = __expf(-(float)j * (9.210340371976184f / 384.0f));
        float sn, cs;
        sincosf((float)s * freq, &sn, &cs);    // accurate range reduction
        tab[idx] = make_float2(cs, sn);
    } else if (n < 6144) {
        // ---- cast X fp32 -> bf16 ----
        size_t i = ((size_t)(n - 3072) * 256 + tid) * 8;
        float4 u = *(const float4*)(X + i);
        float4 v = *(const float4*)(X + i + 4);
        bf16x8 o;
        o[0]=(__bf16)u.x; o[1]=(__bf16)u.y; o[2]=(__bf16)u.z; o[3]=(__bf16)u.w;
        o[4]=(__bf16)v.x; o[5]=(__bf16)v.y; o[6]=(__bf16)v.z; o[7]=(__bf16)v.w;
        *(bf16x8*)(Xb + i) = o;
    } else {
        // ---- weight cast + transpose: Wt[n][k] = (bf16)W[k][n] ----
        int m = n - 6144;                      // 0..575
        int z = m / 144;
        int rem = m - z * 144;
        int by = rem / 12, bx = rem % 12;
        const float* W = z == 0 ? W0 : z == 1 ? W1 : z == 2 ? W2 : W3;
        __bf16*      T = z == 0 ? T0 : z == 1 ? T1 : z == 2 ? T2 : T3;

        const int r0 = by * 64, c0 = bx * 64;
        const int lx = tid & 63, g = tid >> 6;

        #pragma unroll
        for (int rr = 0; rr < 16; ++rr) {
            int r = g * 16 + rr;
            t[r][lx] = W[(size_t)(r0 + r) * D_MODEL + c0 + lx];
        }
        __syncthreads();

        const int nn = tid >> 2;
        const int kb = (tid & 3) * 16;
        bf16x8 o1, o2;
        #pragma unroll
        for (int mm = 0; mm < 8; ++mm) o1[mm] = (__bf16)t[kb + mm][nn];
        #pragma unroll
        for (int mm = 0; mm < 8; ++mm) o2[mm] = (__bf16)t[kb + 8 + mm][nn];
        __bf16* dst = T + (size_t)(c0 + nn) * D_MODEL + r0 + kb;
        *(bf16x8*)dst       = o1;
        *(bf16x8*)(dst + 8) = o2;
    }
}

// ---------------------------------------------------------------------------
// Fused QKV projection (R9 version — best measured of 5 structural variants:
// cooperative LDS staging, BK=64, XCD-swizzled 1D grid lin = c*64 + r so
// XCD = r%8 keeps each XCD's X slice L2-resident; FETCH halved vs R6).
// Q pre-scaled by 0.125 so attention skips the scale.
// ---------------------------------------------------------------------------
__global__ __launch_bounds__(256)
void qkv_gemm(const __bf16* __restrict__ Xb,
              const __bf16* __restrict__ Wqt, const __bf16* __restrict__ Wkt,
              const __bf16* __restrict__ Wvt,
              const float* __restrict__ bq, const float* __restrict__ bk,
              const float* __restrict__ bv,
              const float2* __restrict__ tab,
              __bf16* __restrict__ Qb, __bf16* __restrict__ Kb,
              __bf16* __restrict__ Vtb)
{
    __shared__ bf16x8 Asf[2][8][64];    // 16 KB: [kstep][rowblock][lane]
    __shared__ bf16x8 Bsf[2][8][64];    // 16 KB

    const int tid  = threadIdx.x;
    const int wv   = tid >> 6;
    const int ln   = tid & 63;
    const int t15  = ln & 15;
    const int quad = ln >> 4;
    const int wr = wv >> 1, wc = wv & 1;

    const int lin = blockIdx.x;          // 1152 blocks: c*64 + r
    const int c   = lin >> 6;            // 0..17
    const int r   = lin & 63;            // 0..63  (XCD = r % 8)
    const int which = c / 6;             // 0=Q 1=K 2=V
    const int col0  = (c % 6) * 128;
    const int row0  = r * 128;

    const __bf16* Wt  = which == 0 ? Wqt : which == 1 ? Wkt : Wvt;
    const float* bias = which == 0 ? bq  : which == 1 ? bk  : bv;

    f32x4 acc[4][4];
    #pragma unroll
    for (int i = 0; i < 4; ++i)
        #pragma unroll
        for (int j = 0; j < 4; ++j) acc[i][j] = (f32x4){0.f,0.f,0.f,0.f};

    const __bf16* a0 = Xb + (size_t)(row0 + 16 * wv       + t15) * D_MODEL + 8 * quad;
    const __bf16* a1 = Xb + (size_t)(row0 + 16 * (wv + 4) + t15) * D_MODEL + 8 * quad;
    const __bf16* b0 = Wt + (size_t)(col0 + 16 * wv       + t15) * D_MODEL + 8 * quad;
    const __bf16* b1 = Wt + (size_t)(col0 + 16 * (wv + 4) + t15) * D_MODEL + 8 * quad;

    for (int k0 = 0; k0 < D_MODEL; k0 += 64) {
        __syncthreads();                 // protect prev-iter LDS reads
        #pragma unroll
        for (int ks = 0; ks < 2; ++ks) {
            const int kk = k0 + 32 * ks;
            gload_lds16(a0 + kk, &Asf[ks][wv][0]);
            gload_lds16(a1 + kk, &Asf[ks][wv + 4][0]);
            gload_lds16(b0 + kk, &Bsf[ks][wv][0]);
            gload_lds16(b1 + kk, &Bsf[ks][wv + 4][0]);
        }
        __syncthreads();                 // drain staging

        #pragma unroll
        for (int ks = 0; ks < 2; ++ks) {
            bf16x8 af[4], bfr[4];
            #pragma unroll
            for (int i = 0; i < 4; ++i) af[i]  = Asf[ks][4 * wr + i][ln];
            #pragma unroll
            for (int j = 0; j < 4; ++j) bfr[j] = Bsf[ks][4 * wc + j][ln];
            #pragma unroll
            for (int i = 0; i < 4; ++i)
                #pragma unroll
                for (int j = 0; j < 4; ++j)
                    acc[i][j] = __builtin_amdgcn_mfma_f32_16x16x32_bf16(af[i], bfr[j], acc[i][j], 0, 0, 0);
        }
    }

    #pragma unroll
    for (int i = 0; i < 4; ++i) {
        const int rowb = row0 + 64 * wr + 16 * i + 4 * quad;
        #pragma unroll
        for (int j = 0; j < 4; ++j) {
            const int col = col0 + 64 * wc + 16 * j + t15;
            const float bval = bias[col];
            if (which < 2) {
                const int jh  = col >> 1;
                const float sgn = (col & 1) ? 1.0f : -1.0f;
                const float oscale = (which == 0) ? 0.125f : 1.0f;
                __bf16* dst = (which ? Kb : Qb);
                #pragma unroll
                for (int rr = 0; rr < 4; ++rr) {
                    const int rw = rowb + rr;
                    const int s  = rw & (SEQ - 1);
                    float val  = acc[i][j][rr] + bval;
                    float part = __shfl_xor(val, 1, 64);
                    float2 cs  = tab[(size_t)s * HALF_D + jh];
                    dst[(size_t)rw * D_MODEL + col] = (__bf16)((val * cs.x + part * sgn * cs.y) * oscale);
                }
            } else {
                const int h = col >> 6, d = col & 63;
                const int bidx = rowb >> 11, s = rowb & (SEQ - 1);
                bf16x4 pk;
                #pragma unroll
                for (int rr = 0; rr < 4; ++rr) pk[rr] = (__bf16)(acc[i][j][rr] + bval);
                *(bf16x4*)(Vtb + ((size_t)(bidx * NUM_HEADS + h) * 64 + d) * SEQ + s) = pk;
            }
        }
    }
}

// ---------------------------------------------------------------------------
// Output projection (R9 version): BK=64 cooperative, XCD-swizzled 1D grid.
// ---------------------------------------------------------------------------
__global__ __launch_bounds__(256)
void out_gemm(const __bf16* __restrict__ Ab, const __bf16* __restrict__ Wt,
              const float* __restrict__ bias, float* __restrict__ Cout)
{
    __shared__ bf16x8 Asf[2][8][64];
    __shared__ bf16x8 Bsf[2][8][64];

    const int tid  = threadIdx.x;
    const int wv   = tid >> 6;
    const int ln   = tid & 63;
    const int t15  = ln & 15;
    const int quad = ln >> 4;
    const int wr = wv >> 1, wc = wv & 1;

    const int lin = blockIdx.x;          // 384 blocks: c*64 + r
    const int col0 = (lin >> 6) * 128;
    const int row0 = (lin & 63) * 128;

    f32x4 acc[4][4];
    #pragma unroll
    for (int i = 0; i < 4; ++i)
        #pragma unroll
        for (int j = 0; j < 4; ++j) acc[i][j] = (f32x4){0.f,0.f,0.f,0.f};

    const __bf16* a0 = Ab + (size_t)(row0 + 16 * wv       + t15) * D_MODEL + 8 * quad;
    const __bf16* a1 = Ab + (size_t)(row0 + 16 * (wv + 4) + t15) * D_MODEL + 8 * quad;
    const __bf16* b0 = Wt + (size_t)(col0 + 16 * wv       + t15) * D_MODEL + 8 * quad;
    const __bf16* b1 = Wt + (size_t)(col0 + 16 * (wv + 4) + t15) * D_MODEL + 8 * quad;

    for (int k0 = 0; k0 < D_MODEL; k0 += 64) {
        __syncthreads();
        #pragma unroll
        for (int ks = 0; ks < 2; ++ks) {
            const int kk = k0 + 32 * ks;
            gload_lds16(a0 + kk, &Asf[ks][wv][0]);
            gload_lds16(a1 + kk, &Asf[ks][wv + 4][0]);
            gload_lds16(b0 + kk, &Bsf[ks][wv][0]);
            gload_lds16(b1 + kk, &Bsf[ks][wv + 4][0]);
        }
        __syncthreads();

        #pragma unroll
        for (int ks = 0; ks < 2; ++ks) {
            bf16x8 af[4], bfr[4];
            #pragma unroll
            for (int i = 0; i < 4; ++i) af[i]  = Asf[ks][4 * wr + i][ln];
            #pragma unroll
            for (int j = 0; j < 4; ++j) bfr[j] = Bsf[ks][4 * wc + j][ln];
            #pragma unroll
            for (int i = 0; i < 4; ++i)
                #pragma unroll
                for (int j = 0; j < 4; ++j)
                    acc[i][j] = __builtin_amdgcn_mfma_f32_16x16x32_bf16(af[i], bfr[j], acc[i][j], 0, 0, 0);
        }
    }

    #pragma unroll
    for (int i = 0; i < 4; ++i) {
        const int rowb = row0 + 64 * wr + 16 * i + 4 * quad;
        #pragma unroll
        for (int j = 0; j < 4; ++j) {
            const int col = col0 + 64 * wc + 16 * j + t15;
            const float bval = bias[col];
            #pragma unroll
            for (int rr = 0; rr < 4; ++rr)
                Cout[(size_t)(rowb + rr) * D_MODEL + col] = acc[i][j][rr] + bval;
        }
    }
}

// ---------------------------------------------------------------------------
// Flash attention v4: R6 core (128-q blocks, 8 waves, no-max softmax,
// lane-local l, dbuf K/V, bf16 P via per-wave LDS) +
//  - LPT dispatch: qt = 15 - n/48 (R6's triple remap had 1.7x imbalance:
//    triple sums ranged 21..36 tiles; LPT launches all 32-tile blocks first)
//  - fully-masked waves skip the final tile's compute (wave-uniform guard).
// ---------------------------------------------------------------------------
__device__ __forceinline__ void attn_tile(
    const bf16x8 (*Kbuf)[64], const bf16x8 (*Vbuf)[64],
    __bf16 (*Psw)[72],
    bf16x8 aq0, bf16x8 aq1,
    f32x4* o, float* lacc,
    int ln, int t15, int quad, int j0, int qabs, bool domask)
{
    f32x4 s[4];
    #pragma unroll
    for (int c = 0; c < 4; ++c) {
        s[c] = (f32x4){0.f, 0.f, 0.f, 0.f};
        s[c] = __builtin_amdgcn_mfma_f32_16x16x32_bf16(aq0, Kbuf[c][ln],     s[c], 0, 0, 0);
        s[c] = __builtin_amdgcn_mfma_f32_16x16x32_bf16(aq1, Kbuf[4 + c][ln], s[c], 0, 0, 0);
    }

    float p[4][4];
    #pragma unroll
    for (int c = 0; c < 4; ++c)
        #pragma unroll
        for (int r = 0; r < 4; ++r) {
            float e = __expf(s[c][r]);
            if (domask && (j0 + 16 * c + t15 > qabs + r)) e = 0.f;
            p[c][r] = e;
            lacc[r] += e;
        }

    #pragma unroll
    for (int c = 0; c < 4; ++c)
        #pragma unroll
        for (int r = 0; r < 4; ++r)
            Psw[4 * quad + r][16 * c + t15] = (__bf16)p[c][r];
    __asm__ volatile("s_waitcnt lgkmcnt(0)" ::: "memory");

    bf16x8 ap0 = *(const bf16x8*)&Psw[t15][8 * quad];
    bf16x8 ap1 = *(const bf16x8*)&Psw[t15][32 + 8 * quad];

    #pragma unroll
    for (int c = 0; c < 4; ++c) {
        o[c] = __builtin_amdgcn_mfma_f32_16x16x32_bf16(ap0, Vbuf[c][ln],     o[c], 0, 0, 0);
        o[c] = __builtin_amdgcn_mfma_f32_16x16x32_bf16(ap1, Vbuf[4 + c][ln], o[c], 0, 0, 0);
    }
}

__global__ __launch_bounds__(512)
void attn_flash(const __bf16* __restrict__ Q, const __bf16* __restrict__ K,
                const __bf16* __restrict__ Vt, __bf16* __restrict__ O)
{
    __shared__ bf16x8 Kf[2][8][64];     // 16 KB (double-buffered)
    __shared__ bf16x8 Vf[2][8][64];     // 16 KB
    __shared__ __bf16 Psb[8][16][72];   // 18.4 KB

    const int tid  = threadIdx.x;
    const int wv   = tid >> 6;
    const int ln   = tid & 63;
    const int t15  = ln & 15;
    const int quad = ln >> 4;

    const int n  = blockIdx.x;          // LPT: longest q-tiles dispatched first
    const int qt = 15 - (n / 48);
    const int bh = n % 48;
    const int b  = bh / NUM_HEADS;
    const int h  = bh % NUM_HEADS;
    const int q0 = qt * 128;
    const int nt = (q0 >> 6) + 2;       // 64-key tiles covering [0, q0+128)

    bf16x8 aq0, aq1;
    {
        const __bf16* qs = Q + (size_t)(b * SEQ + q0 + 16 * wv + t15) * D_MODEL + h * 64 + 8 * quad;
        aq0 = *(const bf16x8*)qs;
        aq1 = *(const bf16x8*)(qs + 32);
    }

    const __bf16* kp = K  + ((size_t)b * SEQ + 16 * (wv & 3) + t15) * D_MODEL
                          + h * 64 + 32 * (wv >> 2) + 8 * quad;
    const __bf16* vp = Vt + ((size_t)bh * 64 + 16 * (wv & 3) + t15) * SEQ
                          + 32 * (wv >> 2) + 8 * quad;

    f32x4 o[4];
    #pragma unroll
    for (int c = 0; c < 4; ++c) o[c] = (f32x4){0.f,0.f,0.f,0.f};
    float lacc[4] = {0.f, 0.f, 0.f, 0.f};
    const int qabs = q0 + 16 * wv + 4 * quad;
    const int wmax = q0 + 16 * wv + 15;  // last q-row this wave owns

    gload_lds16(kp, &Kf[0][wv][0]);
    gload_lds16(vp, &Vf[0][wv][0]);

    int cur = 0;
    for (int it = 0; it < nt; ++it) {
        __syncthreads();
        if (it + 1 < nt) {
            const int jn = (it + 1) * 64;
            gload_lds16(kp + (size_t)jn * D_MODEL, &Kf[cur ^ 1][wv][0]);
            gload_lds16(vp + jn,                   &Vf[cur ^ 1][wv][0]);
        }
        const int j0 = it * 64;
        if (j0 <= wmax) {                // skip fully-masked tiles (wave-uniform)
            const bool domask = (j0 + 63) > (q0 + 16 * wv);
            attn_tile(Kf[cur], Vf[cur], Psb[wv], aq0, aq1, o, lacc,
                      ln, t15, quad, j0, qabs, domask);
        }
        cur ^= 1;
    }

    #pragma unroll
    for (int off = 1; off < 16; off <<= 1)
        #pragma unroll
        for (int r = 0; r < 4; ++r)
            lacc[r] += __shfl_xor(lacc[r], off, 64);

    float inv[4];
    #pragma unroll
    for (int r = 0; r < 4; ++r) inv[r] = 1.0f / lacc[r];
    #pragma unroll
    for (int c = 0; c < 4; ++c)
        #pragma unroll
        for (int r = 0; r < 4; ++r) {
            int row = qabs + r;
            O[(size_t)(b * SEQ + row) * D_MODEL + h * 64 + 16 * c + t15] = (__bf16)(o[c][r] * inv[r]);
        }
}

// ---------------------------------------------------------------------------
extern "C" void kernel_launch(void* const* d_in, const int* in_sizes, int n_in,
                              void* d_out, int out_size, void* d_ws, size_t ws_size,
                              hipStream_t stream) {
    const float* X  = (const float*)d_in[0];
    const float* Wq = (const float*)d_in[1];
    const float* bq = (const float*)d_in[2];
    const float* Wk = (const float*)d_in[3];
    const float* bk = (const float*)d_in[4];
    const float* Wv = (const float*)d_in[5];
    const float* bv = (const float*)d_in[6];
    const float* Wo = (const float*)d_in[7];
    const float* bo = (const float*)d_in[8];
    float* out = (float*)d_out;

    const size_t BSD = (size_t)MROWS * D_MODEL;   // 6,291,456
    const size_t WSZ = (size_t)D_MODEL * D_MODEL; //   589,824

    __bf16* Xb  = (__bf16*)d_ws;
    __bf16* Qb  = Xb  + BSD;
    __bf16* Kb  = Qb  + BSD;
    __bf16* Vtb = Kb  + BSD;
    __bf16* Ob  = Vtb + BSD;
    __bf16* Wqt = Ob  + BSD;
    __bf16* Wkt = Wqt + WSZ;
    __bf16* Wvt = Wkt + WSZ;
    __bf16* Wot = Wvt + WSZ;
    float2* Tab = (float2*)(Wot + WSZ);

    prep<<<6720, 256, 0, stream>>>(X, Xb, Wq, Wk, Wv, Wo, Wqt, Wkt, Wvt, Wot, Tab);

    qkv_gemm<<<1152, 256, 0, stream>>>(Xb, Wqt, Wkt, Wvt, bq, bk, bv, Tab, Qb, Kb, Vtb);

    attn_flash<<<768, 512, 0, stream>>>(Qb, Kb, Vtb, Ob);

    out_gemm<<<384, 256, 0, stream>>>(Ob, Wot, bo, out);
}

// Round 12
// 250.693 us; speedup vs baseline: 1.2466x; 1.0532x over previous
//
#include <hip/hip_runtime.h>
#include <math.h>

#define D_MODEL 768
#define NUM_HEADS 12
#define HEAD_DIM 64
#define SEQ 2048
#define BATCH 4
#define MROWS (BATCH * SEQ)   // 8192
#define HALF_D (D_MODEL / 2)  // 384

typedef __bf16 bf16x8 __attribute__((ext_vector_type(8)));
typedef __bf16 bf16x4 __attribute__((ext_vector_type(4)));
typedef float  f32x4  __attribute__((ext_vector_type(4)));

// async global->LDS, 16B per lane; LDS dest = wave-uniform base + lane*16
__device__ __forceinline__ void gload_lds16(const void* gp, void* lp) {
    __builtin_amdgcn_global_load_lds(
        (const __attribute__((address_space(1))) unsigned int*)gp,
        (__attribute__((address_space(3))) unsigned int*)lp, 16, 0, 0);
}

// ---------------------------------------------------------------------------
// prep: X cast (blocks [0,3072)) + weight cast/transpose ([3072,3648)).
// RoPE table removed — qkv computes trig inline with native v_exp/v_sin/v_cos.
// ---------------------------------------------------------------------------
__global__ __launch_bounds__(256)
void prep(const float* __restrict__ X, __bf16* __restrict__ Xb,
          const float* __restrict__ W0, const float* __restrict__ W1,
          const float* __restrict__ W2, const float* __restrict__ W3,
          __bf16* __restrict__ T0, __bf16* __restrict__ T1,
          __bf16* __restrict__ T2, __bf16* __restrict__ T3)
{
    __shared__ float t[64][65];
    const int n   = blockIdx.x;
    const int tid = threadIdx.x;

    if (n < 3072) {
        // ---- cast X fp32 -> bf16 ----
        size_t i = ((size_t)n * 256 + tid) * 8;
        float4 u = *(const float4*)(X + i);
        float4 v = *(const float4*)(X + i + 4);
        bf16x8 o;
        o[0]=(__bf16)u.x; o[1]=(__bf16)u.y; o[2]=(__bf16)u.z; o[3]=(__bf16)u.w;
        o[4]=(__bf16)v.x; o[5]=(__bf16)v.y; o[6]=(__bf16)v.z; o[7]=(__bf16)v.w;
        *(bf16x8*)(Xb + i) = o;
    } else {
        // ---- weight cast + transpose: Wt[n][k] = (bf16)W[k][n] ----
        int m = n - 3072;                      // 0..575
        int z = m / 144;
        int rem = m - z * 144;
        int by = rem / 12, bx = rem % 12;
        const float* W = z == 0 ? W0 : z == 1 ? W1 : z == 2 ? W2 : W3;
        __bf16*      T = z == 0 ? T0 : z == 1 ? T1 : z == 2 ? T2 : T3;

        const int r0 = by * 64, c0 = bx * 64;
        const int lx = tid & 63, g = tid >> 6;

        #pragma unroll
        for (int rr = 0; rr < 16; ++rr) {
            int r = g * 16 + rr;
            t[r][lx] = W[(size_t)(r0 + r) * D_MODEL + c0 + lx];
        }
        __syncthreads();

        const int nn = tid >> 2;
        const int kb = (tid & 3) * 16;
        bf16x8 o1, o2;
        #pragma unroll
        for (int mm = 0; mm < 8; ++mm) o1[mm] = (__bf16)t[kb + mm][nn];
        #pragma unroll
        for (int mm = 0; mm < 8; ++mm) o2[mm] = (__bf16)t[kb + 8 + mm][nn];
        __bf16* dst = T + (size_t)(c0 + nn) * D_MODEL + r0 + kb;
        *(bf16x8*)dst       = o1;
        *(bf16x8*)(dst + 8) = o2;
    }
}

// ---------------------------------------------------------------------------
// Fused QKV projection (R9 structure — best of 6 variants: cooperative LDS
// staging, BK=64, XCD-swizzled 1D grid). RoPE now inline via native
// v_exp/v_sin/v_cos (no OCML calls -> no spill; error ~4e-3 worst, in budget).
// Q pre-scaled by 0.125 so attention skips the scale.
// ---------------------------------------------------------------------------
__global__ __launch_bounds__(256)
void qkv_gemm(const __bf16* __restrict__ Xb,
              const __bf16* __restrict__ Wqt, const __bf16* __restrict__ Wkt,
              const __bf16* __restrict__ Wvt,
              const float* __restrict__ bq, const float* __restrict__ bk,
              const float* __restrict__ bv,
              __bf16* __restrict__ Qb, __bf16* __restrict__ Kb,
              __bf16* __restrict__ Vtb)
{
    __shared__ bf16x8 Asf[2][8][64];    // 16 KB: [kstep][rowblock][lane]
    __shared__ bf16x8 Bsf[2][8][64];    // 16 KB

    const int tid  = threadIdx.x;
    const int wv   = tid >> 6;
    const int ln   = tid & 63;
    const int t15  = ln & 15;
    const int quad = ln >> 4;
    const int wr = wv >> 1, wc = wv & 1;

    const int lin = blockIdx.x;          // 1152 blocks: c*64 + r
    const int c   = lin >> 6;            // 0..17
    const int r   = lin & 63;            // 0..63  (XCD = r % 8)
    const int which = c / 6;             // 0=Q 1=K 2=V
    const int col0  = (c % 6) * 128;
    const int row0  = r * 128;

    const __bf16* Wt  = which == 0 ? Wqt : which == 1 ? Wkt : Wvt;
    const float* bias = which == 0 ? bq  : which == 1 ? bk  : bv;

    f32x4 acc[4][4];
    #pragma unroll
    for (int i = 0; i < 4; ++i)
        #pragma unroll
        for (int j = 0; j < 4; ++j) acc[i][j] = (f32x4){0.f,0.f,0.f,0.f};

    const __bf16* a0 = Xb + (size_t)(row0 + 16 * wv       + t15) * D_MODEL + 8 * quad;
    const __bf16* a1 = Xb + (size_t)(row0 + 16 * (wv + 4) + t15) * D_MODEL + 8 * quad;
    const __bf16* b0 = Wt + (size_t)(col0 + 16 * wv       + t15) * D_MODEL + 8 * quad;
    const __bf16* b1 = Wt + (size_t)(col0 + 16 * (wv + 4) + t15) * D_MODEL + 8 * quad;

    for (int k0 = 0; k0 < D_MODEL; k0 += 64) {
        __syncthreads();                 // protect prev-iter LDS reads
        #pragma unroll
        for (int ks = 0; ks < 2; ++ks) {
            const int kk = k0 + 32 * ks;
            gload_lds16(a0 + kk, &Asf[ks][wv][0]);
            gload_lds16(a1 + kk, &Asf[ks][wv + 4][0]);
            gload_lds16(b0 + kk, &Bsf[ks][wv][0]);
            gload_lds16(b1 + kk, &Bsf[ks][wv + 4][0]);
        }
        __syncthreads();                 // drain staging

        #pragma unroll
        for (int ks = 0; ks < 2; ++ks) {
            bf16x8 af[4], bfr[4];
            #pragma unroll
            for (int i = 0; i < 4; ++i) af[i]  = Asf[ks][4 * wr + i][ln];
            #pragma unroll
            for (int j = 0; j < 4; ++j) bfr[j] = Bsf[ks][4 * wc + j][ln];
            #pragma unroll
            for (int i = 0; i < 4; ++i)
                #pragma unroll
                for (int j = 0; j < 4; ++j)
                    acc[i][j] = __builtin_amdgcn_mfma_f32_16x16x32_bf16(af[i], bfr[j], acc[i][j], 0, 0, 0);
        }
    }

    #pragma unroll
    for (int i = 0; i < 4; ++i) {
        const int rowb = row0 + 64 * wr + 16 * i + 4 * quad;
        #pragma unroll
        for (int j = 0; j < 4; ++j) {
            const int col = col0 + 64 * wc + 16 * j + t15;
            const float bval = bias[col];
            if (which < 2) {
                // inline RoPE: freq = 10000^(-ne/768) via native exp; pair via lane^1
                const int ne = col & ~1;
                const float fr = __expf((float)ne * (-9.210340371976184f / 768.0f));
                const float sgn = (col & 1) ? 1.0f : -1.0f;
                const float oscale = (which == 0) ? 0.125f : 1.0f;
                __bf16* dst = (which ? Kb : Qb);
                #pragma unroll
                for (int rr = 0; rr < 4; ++rr) {
                    const int rw = rowb + rr;
                    const int s  = rw & (SEQ - 1);
                    float val  = acc[i][j][rr] + bval;
                    float part = __shfl_xor(val, 1, 64);
                    float ang  = (float)s * fr;
                    float cs   = __cosf(ang);          // native v_cos
                    float sn   = __sinf(ang);          // native v_sin
                    dst[(size_t)rw * D_MODEL + col] = (__bf16)((val * cs + part * sgn * sn) * oscale);
                }
            } else {
                const int h = col >> 6, d = col & 63;
                const int bidx = rowb >> 11, s = rowb & (SEQ - 1);
                bf16x4 pk;
                #pragma unroll
                for (int rr = 0; rr < 4; ++rr) pk[rr] = (__bf16)(acc[i][j][rr] + bval);
                *(bf16x4*)(Vtb + ((size_t)(bidx * NUM_HEADS + h) * 64 + d) * SEQ + s) = pk;
            }
        }
    }
}

// ---------------------------------------------------------------------------
// Output projection v4: 64x128 tile, 768 blocks = exactly 3/CU (the 128x128
// version had 384 blocks = 1.5/CU: half the CUs got 2 blocks -> 2x tail).
// 4 waves, each 32 rows x 64 cols (2x4 acc). 24 staged chunks/iter, 6/wave.
// LDS 24 KB. XCD swizzle: lin = c*128 + r.
// ---------------------------------------------------------------------------
__global__ __launch_bounds__(256)
void out_gemm(const __bf16* __restrict__ Ab, const __bf16* __restrict__ Wt,
              const float* __restrict__ bias, float* __restrict__ Cout)
{
    __shared__ bf16x8 Asf[2][4][64];    // 8 KB
    __shared__ bf16x8 Bsf[2][8][64];    // 16 KB

    const int tid  = threadIdx.x;
    const int wv   = tid >> 6;
    const int ln   = tid & 63;
    const int t15  = ln & 15;
    const int quad = ln >> 4;
    const int wr = wv >> 1, wc = wv & 1;   // wave tile: rows 32*wr, cols 64*wc

    const int lin  = blockIdx.x;         // 768 blocks: c*128 + r
    const int col0 = (lin >> 7) * 128;   // 0..5
    const int row0 = (lin & 127) * 64;   // XCD = r % 8

    f32x4 acc[2][4];
    #pragma unroll
    for (int i = 0; i < 2; ++i)
        #pragma unroll
        for (int j = 0; j < 4; ++j) acc[i][j] = (f32x4){0.f,0.f,0.f,0.f};

    for (int k0 = 0; k0 < D_MODEL; k0 += 64) {
        __syncthreads();
        // 24 chunks: id = ks*12 + w; w<4 -> A rowblock w, else B colblock w-4.
        #pragma unroll
        for (int u = 0; u < 6; ++u) {
            const int id = wv * 6 + u;
            const int ks = id / 12;
            const int w  = id % 12;
            if (w < 4) {
                const __bf16* src = Ab + (size_t)(row0 + 16 * w + t15) * D_MODEL
                                       + k0 + 32 * ks + 8 * quad;
                gload_lds16(src, &Asf[ks][w][0]);
            } else {
                const __bf16* src = Wt + (size_t)(col0 + 16 * (w - 4) + t15) * D_MODEL
                                       + k0 + 32 * ks + 8 * quad;
                gload_lds16(src, &Bsf[ks][w - 4][0]);
            }
        }
        __syncthreads();

        #pragma unroll
        for (int ks = 0; ks < 2; ++ks) {
            bf16x8 af[2], bfr[4];
            #pragma unroll
            for (int i = 0; i < 2; ++i) af[i]  = Asf[ks][2 * wr + i][ln];
            #pragma unroll
            for (int j = 0; j < 4; ++j) bfr[j] = Bsf[ks][4 * wc + j][ln];
            #pragma unroll
            for (int i = 0; i < 2; ++i)
                #pragma unroll
                for (int j = 0; j < 4; ++j)
                    acc[i][j] = __builtin_amdgcn_mfma_f32_16x16x32_bf16(af[i], bfr[j], acc[i][j], 0, 0, 0);
        }
    }

    #pragma unroll
    for (int i = 0; i < 2; ++i) {
        const int rowb = row0 + 32 * wr + 16 * i + 4 * quad;
        #pragma unroll
        for (int j = 0; j < 4; ++j) {
            const int col = col0 + 64 * wc + 16 * j + t15;
            const float bval = bias[col];
            #pragma unroll
            for (int rr = 0; rr < 4; ++rr)
                Cout[(size_t)(rowb + rr) * D_MODEL + col] = acc[i][j][rr] + bval;
        }
    }
}

// ---------------------------------------------------------------------------
// Flash attention v4 (unchanged from R11): 128-q blocks, 8 waves, no-max
// softmax, lane-local l, dbuf K/V, bf16 P via per-wave LDS, LPT dispatch,
// fully-masked-tile skip.
// ---------------------------------------------------------------------------
__device__ __forceinline__ void attn_tile(
    const bf16x8 (*Kbuf)[64], const bf16x8 (*Vbuf)[64],
    __bf16 (*Psw)[72],
    bf16x8 aq0, bf16x8 aq1,
    f32x4* o, float* lacc,
    int ln, int t15, int quad, int j0, int qabs, bool domask)
{
    f32x4 s[4];
    #pragma unroll
    for (int c = 0; c < 4; ++c) {
        s[c] = (f32x4){0.f, 0.f, 0.f, 0.f};
        s[c] = __builtin_amdgcn_mfma_f32_16x16x32_bf16(aq0, Kbuf[c][ln],     s[c], 0, 0, 0);
        s[c] = __builtin_amdgcn_mfma_f32_16x16x32_bf16(aq1, Kbuf[4 + c][ln], s[c], 0, 0, 0);
    }

    float p[4][4];
    #pragma unroll
    for (int c = 0; c < 4; ++c)
        #pragma unroll
        for (int r = 0; r < 4; ++r) {
            float e = __expf(s[c][r]);
            if (domask && (j0 + 16 * c + t15 > qabs + r)) e = 0.f;
            p[c][r] = e;
            lacc[r] += e;
        }

    #pragma unroll
    for (int c = 0; c < 4; ++c)
        #pragma unroll
        for (int r = 0; r < 4; ++r)
            Psw[4 * quad + r][16 * c + t15] = (__bf16)p[c][r];
    __asm__ volatile("s_waitcnt lgkmcnt(0)" ::: "memory");

    bf16x8 ap0 = *(const bf16x8*)&Psw[t15][8 * quad];
    bf16x8 ap1 = *(const bf16x8*)&Psw[t15][32 + 8 * quad];

    #pragma unroll
    for (int c = 0; c < 4; ++c) {
        o[c] = __builtin_amdgcn_mfma_f32_16x16x32_bf16(ap0, Vbuf[c][ln],     o[c], 0, 0, 0);
        o[c] = __builtin_amdgcn_mfma_f32_16x16x32_bf16(ap1, Vbuf[4 + c][ln], o[c], 0, 0, 0);
    }
}

__global__ __launch_bounds__(512)
void attn_flash(const __bf16* __restrict__ Q, const __bf16* __restrict__ K,
                const __bf16* __restrict__ Vt, __bf16* __restrict__ O)
{
    __shared__ bf16x8 Kf[2][8][64];     // 16 KB (double-buffered)
    __shared__ bf16x8 Vf[2][8][64];     // 16 KB
    __shared__ __bf16 Psb[8][16][72];   // 18.4 KB

    const int tid  = threadIdx.x;
    const int wv   = tid >> 6;
    const int ln   = tid & 63;
    const int t15  = ln & 15;
    const int quad = ln >> 4;

    const int n  = blockIdx.x;          // LPT: longest q-tiles dispatched first
    const int qt = 15 - (n / 48);
    const int bh = n % 48;
    const int b  = bh / NUM_HEADS;
    const int h  = bh % NUM_HEADS;
    const int q0 = qt * 128;
    const int nt = (q0 >> 6) + 2;       // 64-key tiles covering [0, q0+128)

    bf16x8 aq0, aq1;
    {
        const __bf16* qs = Q + (size_t)(b * SEQ + q0 + 16 * wv + t15) * D_MODEL + h * 64 + 8 * quad;
        aq0 = *(const bf16x8*)qs;
        aq1 = *(const bf16x8*)(qs + 32);
    }

    const __bf16* kp = K  + ((size_t)b * SEQ + 16 * (wv & 3) + t15) * D_MODEL
                          + h * 64 + 32 * (wv >> 2) + 8 * quad;
    const __bf16* vp = Vt + ((size_t)bh * 64 + 16 * (wv & 3) + t15) * SEQ
                          + 32 * (wv >> 2) + 8 * quad;

    f32x4 o[4];
    #pragma unroll
    for (int c = 0; c < 4; ++c) o[c] = (f32x4){0.f,0.f,0.f,0.f};
    float lacc[4] = {0.f, 0.f, 0.f, 0.f};
    const int qabs = q0 + 16 * wv + 4 * quad;
    const int wmax = q0 + 16 * wv + 15;  // last q-row this wave owns

    gload_lds16(kp, &Kf[0][wv][0]);
    gload_lds16(vp, &Vf[0][wv][0]);

    int cur = 0;
    for (int it = 0; it < nt; ++it) {
        __syncthreads();
        if (it + 1 < nt) {
            const int jn = (it + 1) * 64;
            gload_lds16(kp + (size_t)jn * D_MODEL, &Kf[cur ^ 1][wv][0]);
            gload_lds16(vp + jn,                   &Vf[cur ^ 1][wv][0]);
        }
        const int j0 = it * 64;
        if (j0 <= wmax) {                // skip fully-masked tiles (wave-uniform)
            const bool domask = (j0 + 63) > (q0 + 16 * wv);
            attn_tile(Kf[cur], Vf[cur], Psb[wv], aq0, aq1, o, lacc,
                      ln, t15, quad, j0, qabs, domask);
        }
        cur ^= 1;
    }

    #pragma unroll
    for (int off = 1; off < 16; off <<= 1)
        #pragma unroll
        for (int r = 0; r < 4; ++r)
            lacc[r] += __shfl_xor(lacc[r], off, 64);

    float inv[4];
    #pragma unroll
    for (int r = 0; r < 4; ++r) inv[r] = 1.0f / lacc[r];
    #pragma unroll
    for (int c = 0; c < 4; ++c)
        #pragma unroll
        for (int r = 0; r < 4; ++r) {
            int row = qabs + r;
            O[(size_t)(b * SEQ + row) * D_MODEL + h * 64 + 16 * c + t15] = (__bf16)(o[c][r] * inv[r]);
        }
}

// ---------------------------------------------------------------------------
extern "C" void kernel_launch(void* const* d_in, const int* in_sizes, int n_in,
                              void* d_out, int out_size, void* d_ws, size_t ws_size,
                              hipStream_t stream) {
    const float* X  = (const float*)d_in[0];
    const float* Wq = (const float*)d_in[1];
    const float* bq = (const float*)d_in[2];
    const float* Wk = (const float*)d_in[3];
    const float* bk = (const float*)d_in[4];
    const float* Wv = (const float*)d_in[5];
    const float* bv = (const float*)d_in[6];
    const float* Wo = (const float*)d_in[7];
    const float* bo = (const float*)d_in[8];
    float* out = (float*)d_out;

    const size_t BSD = (size_t)MROWS * D_MODEL;   // 6,291,456
    const size_t WSZ = (size_t)D_MODEL * D_MODEL; //   589,824

    __bf16* Xb  = (__bf16*)d_ws;
    __bf16* Qb  = Xb  + BSD;
    __bf16* Kb  = Qb  + BSD;
    __bf16* Vtb = Kb  + BSD;
    __bf16* Ob  = Vtb + BSD;
    __bf16* Wqt = Ob  + BSD;
    __bf16* Wkt = Wqt + WSZ;
    __bf16* Wvt = Wkt + WSZ;
    __bf16* Wot = Wvt + WSZ;

    prep<<<3648, 256, 0, stream>>>(X, Xb, Wq, Wk, Wv, Wo, Wqt, Wkt, Wvt, Wot);

    qkv_gemm<<<1152, 256, 0, stream>>>(Xb, Wqt, Wkt, Wvt, bq, bk, bv, Qb, Kb, Vtb);

    attn_flash<<<768, 512, 0, stream>>>(Qb, Kb, Vtb, Ob);

    out_gemm<<<768, 256, 0, stream>>>(Ob, Wot, bo, out);
}